// Round 6
// baseline (197.160 us; speedup 1.0000x reference)
//
#include <hip/hip_runtime.h>
#include <hip/hip_bf16.h>

typedef __attribute__((ext_vector_type(8))) __bf16 bf16x8;
typedef __attribute__((ext_vector_type(4))) float f32x4;

#define LN2F 0.6931471805599453f

__device__ __forceinline__ void gload16(const void* g, void* l) {
  __builtin_amdgcn_global_load_lds(
      (const __attribute__((address_space(1))) void*)g,
      (__attribute__((address_space(3))) void*)l, 16, 0, 0);
}

// ---------------------------------------------------------------------------
// Global bf16 layouts:
//   Xb: 32 mtiles x 16 ktiles, tile = 128 rows x 64 k = 8192 elems, in-tile
//       elem off = r*64 + ((s*8) ^ ((r&7)<<3))   (16B-granule XOR swizzle)
//   Kb: 128 ntiles x 16 ktiles, same in-tile layout (rows = output cols).
// ---------------------------------------------------------------------------

__global__ void k_cvt_x(const float* __restrict__ x, const float* __restrict__ vbias,
                        __bf16* __restrict__ Xb, float* __restrict__ out) {
  int t = threadIdx.x;
  int row = blockIdx.x * 2 + (t >> 7);
  int slot = t & 127;
  const float4* xp = (const float4*)(x + (size_t)row * 1024 + (size_t)slot * 8);
  float4 v0 = xp[0], v1 = xp[1];
  bf16x8 h;
  h[0] = (__bf16)v0.x; h[1] = (__bf16)v0.y; h[2] = (__bf16)v0.z; h[3] = (__bf16)v0.w;
  h[4] = (__bf16)v1.x; h[5] = (__bf16)v1.y; h[6] = (__bf16)v1.z; h[7] = (__bf16)v1.w;
  int kt = slot >> 3, si = slot & 7;
  int r = row & 127;
  size_t off = ((size_t)((row >> 7) * 16 + kt)) * 8192 + (size_t)r * 64 + ((si * 8) ^ ((r & 7) << 3));
  *(bf16x8*)(Xb + off) = h;
  float s = v0.x + v0.y + v0.z + v0.w + v1.x + v1.y + v1.z + v1.w;
  #pragma unroll
  for (int m = 32; m; m >>= 1) s += __shfl_down(s, m);
  if ((t & 63) == 0) atomicAdd(out + row, vbias[0] * s);
}

// expand via LDS-staged W column + aligned b128 reads + uniform short-shift.
#define SH_(a) ((wd[a] >> 16) | (wd[(a) + 1] << 16))
#define MK4_(a) make_uint4(wd[a], wd[(a) + 1], wd[(a) + 2], wd[(a) + 3])
#define MKS_(a) make_uint4(SH_(a), SH_((a) + 1), SH_((a) + 2), SH_((a) + 3))

__global__ void k_expand2(const float* __restrict__ W, __bf16* __restrict__ Kb) {
  __shared__ __align__(16) unsigned short LW[1064];
  int h0 = blockIdx.x * 32;
  int j = h0 >> 10;
  int kh0 = h0 & 1023;
  int tid = threadIdx.x;
  for (int i = tid; i < 1056; i += 256) {
    __bf16 b = (__bf16)W[((kh0 + i) & 1023) * 16 + j];
    LW[i] = *(unsigned short*)&b;
  }
  __syncthreads();
  int wv = tid >> 6, lane = tid & 63;
  #pragma unroll
  for (int hi = 0; hi < 8; ++hi) {
    int h = h0 + hi * 4 + wv;
    int kh = h & 1023;
    int c = kh & 7;
    int base_e = (kh & ~7) - kh0;
    #pragma unroll
    for (int sl = 0; sl < 2; ++sl) {
      int s = lane + sl * 64;
      int i0 = (s >> 3) * 64 + (s & 7) * 8;
      const uint4* p = (const uint4*)(LW + base_e + i0);
      uint4 q0 = p[0], q1 = p[1];
      uint wd[8] = {q0.x, q0.y, q0.z, q0.w, q1.x, q1.y, q1.z, q1.w};
      uint4 o;
      switch (c) {
        case 0: o = MK4_(0); break;
        case 1: o = MKS_(0); break;
        case 2: o = MK4_(1); break;
        case 3: o = MKS_(1); break;
        case 4: o = MK4_(2); break;
        case 5: o = MKS_(2); break;
        case 6: o = MK4_(3); break;
        default: o = MKS_(3); break;
      }
      int r = h & 127;
      size_t off = ((size_t)((h >> 7) * 16 + (s >> 3))) * 8192 + (size_t)r * 64 +
                   (((s & 7) * 8) ^ ((r & 7) << 3));
      *(uint4*)(Kb + off) = o;
    }
  }
}

// GEMM 256x256x64, 512 thr = 8 waves (2M x 4N), per-wave 128x64.
// m201-style 4-phase schedule per K-tile: each phase = {issue next phase's
// ds_reads (+stage at P0) | barrier | 16 MFMA (operands read LAST phase) |
// barrier}. DS and MFMA pipes overlap phase-by-phase instead of colliding.
// vmcnt(0) drained at end of P2 (2.5 phases after stage issue) + barrier
// before the cross-buffer reads at P3.
__global__ __launch_bounds__(512, 2) void k_gemm_lc6(
    const __bf16* __restrict__ Xb, const __bf16* __restrict__ Kb,
    const float* __restrict__ bsymm, float* __restrict__ out) {
  __shared__ __align__(16) __bf16 As[32768];   // 2 buf x 16384
  __shared__ __align__(16) __bf16 Bs[32768];

  int hw = blockIdx.x;
  int wg = (hw & 7) * 128 + (hw >> 3);   // XCD swizzle (1024 % 8 == 0)
  int by = wg & 15, bx = wg >> 4;
  int tid = threadIdx.x, w = tid >> 6, lane = tid & 63;
  int wm = w >> 2, wn = w & 3;
  int lr = lane & 15, lk = lane >> 4;

  const __bf16* ga[4]; const __bf16* gb[4];   // advance 8192 elems / K-tile
  {
    const __bf16* a0p = Xb + ((size_t)(2 * by) * 16) * 8192 + w * 512 + lane * 8;
    const __bf16* a1p = Xb + ((size_t)(2 * by + 1) * 16) * 8192 + w * 512 + lane * 8;
    ga[0] = a0p; ga[1] = a0p + 4096; ga[2] = a1p; ga[3] = a1p + 4096;
    const __bf16* b0p = Kb + ((size_t)(2 * bx) * 16) * 8192 + w * 512 + lane * 8;
    const __bf16* b1p = Kb + ((size_t)(2 * bx + 1) * 16) * 8192 + w * 512 + lane * 8;
    gb[0] = b0p; gb[1] = b0p + 4096; gb[2] = b1p; gb[3] = b1p + 4096;
  }
  const __bf16 *pa[2][2], *pb[2][2];          // [buf][kh] LDS read bases
  {
    int lx0 = lr * 64 + ((lk * 8) ^ ((lr & 7) << 3));
    int lx1 = lr * 64 + (((4 + lk) * 8) ^ ((lr & 7) << 3));
    pa[0][0] = As + wm * 8192 + lx0;  pa[0][1] = As + wm * 8192 + lx1;
    pa[1][0] = pa[0][0] + 16384;      pa[1][1] = pa[0][1] + 16384;
    int bo = (wn >> 1) * 8192 + (wn & 1) * 4096;
    pb[0][0] = Bs + bo + lx0;         pb[0][1] = Bs + bo + lx1;
    pb[1][0] = pb[0][0] + 16384;      pb[1][1] = pb[0][1] + 16384;
  }

  f32x4 acc[8][4] = {};
  bf16x8 a0[4], a1[4], a2[4], a3[4], b0[4], b1[4];

#define STAGE(BUF) do { \
    gload16(ga[0], As + (BUF) * 16384 + w * 512); \
    gload16(ga[1], As + (BUF) * 16384 + w * 512 + 4096); \
    gload16(ga[2], As + (BUF) * 16384 + 8192 + w * 512); \
    gload16(ga[3], As + (BUF) * 16384 + 8192 + w * 512 + 4096); \
    gload16(gb[0], Bs + (BUF) * 16384 + w * 512); \
    gload16(gb[1], Bs + (BUF) * 16384 + w * 512 + 4096); \
    gload16(gb[2], Bs + (BUF) * 16384 + 8192 + w * 512); \
    gload16(gb[3], Bs + (BUF) * 16384 + 8192 + w * 512 + 4096); \
    ga[0] += 8192; ga[1] += 8192; ga[2] += 8192; ga[3] += 8192; \
    gb[0] += 8192; gb[1] += 8192; gb[2] += 8192; gb[3] += 8192; \
  } while (0)

#define MFMA16(AOFF, A, B) do { \
    __builtin_amdgcn_s_setprio(1); \
    _Pragma("unroll") for (int m = 0; m < 4; ++m) \
      _Pragma("unroll") for (int n = 0; n < 4; ++n) \
        acc[(AOFF) + m][n] = __builtin_amdgcn_mfma_f32_16x16x32_bf16( \
            A[m], B[n], acc[(AOFF) + m][n], 0, 0, 0); \
    __builtin_amdgcn_s_setprio(0); \
  } while (0)

#define TILE8(BUF, LAST) do { \
    /* P0: operands a0,b0 pending from prev P3 */ \
    if (!(LAST)) STAGE((BUF) ^ 1); \
    _Pragma("unroll") for (int m = 0; m < 4; ++m) \
      a1[m] = *(const bf16x8*)(pa[BUF][0] + 4096 + m * 1024); \
    __builtin_amdgcn_sched_barrier(0); \
    __builtin_amdgcn_s_barrier(); \
    MFMA16(0, a0, b0); \
    __builtin_amdgcn_s_barrier(); \
    /* P1 */ \
    _Pragma("unroll") for (int n = 0; n < 4; ++n) \
      b1[n] = *(const bf16x8*)(pb[BUF][1] + n * 1024); \
    _Pragma("unroll") for (int m = 0; m < 4; ++m) \
      a2[m] = *(const bf16x8*)(pa[BUF][1] + m * 1024); \
    __builtin_amdgcn_sched_barrier(0); \
    __builtin_amdgcn_s_barrier(); \
    MFMA16(4, a1, b0); \
    __builtin_amdgcn_s_barrier(); \
    /* P2 */ \
    _Pragma("unroll") for (int m = 0; m < 4; ++m) \
      a3[m] = *(const bf16x8*)(pa[BUF][1] + 4096 + m * 1024); \
    __builtin_amdgcn_sched_barrier(0); \
    __builtin_amdgcn_s_barrier(); \
    MFMA16(0, a2, b1); \
    asm volatile("s_waitcnt vmcnt(0)" ::: "memory"); /* stage(t+1) landed */ \
    __builtin_amdgcn_sched_barrier(0); \
    __builtin_amdgcn_s_barrier();   /* all waves' DMA drained -> buf^1 valid */ \
    /* P3: read next tile's first operands from buf^1 */ \
    if (!(LAST)) { \
      _Pragma("unroll") for (int n = 0; n < 4; ++n) \
        b0[n] = *(const bf16x8*)(pb[(BUF) ^ 1][0] + n * 1024); \
      _Pragma("unroll") for (int m = 0; m < 4; ++m) \
        a0[m] = *(const bf16x8*)(pa[(BUF) ^ 1][0] + m * 1024); \
    } \
    __builtin_amdgcn_sched_barrier(0); \
    __builtin_amdgcn_s_barrier(); \
    MFMA16(4, a3, b1); \
    __builtin_amdgcn_s_barrier(); \
  } while (0)

  STAGE(0);
  asm volatile("s_waitcnt vmcnt(0)" ::: "memory");
  __builtin_amdgcn_sched_barrier(0);
  __builtin_amdgcn_s_barrier();
  #pragma unroll
  for (int n = 0; n < 4; ++n)
    b0[n] = *(const bf16x8*)(pb[0][0] + n * 1024);
  #pragma unroll
  for (int m = 0; m < 4; ++m)
    a0[m] = *(const bf16x8*)(pa[0][0] + m * 1024);

  #pragma unroll 1
  for (int tt = 0; tt < 7; ++tt) { TILE8(0, 0); TILE8(1, 0); }
  TILE8(0, 0);
  TILE8(1, 1);

#undef TILE8
#undef MFMA16
#undef STAGE

  // epilogue: bias + logcosh + reduce over wave's 64 cols, atomicAdd per row
  float bias = bsymm[bx >> 2];
  #pragma unroll
  for (int m = 0; m < 8; ++m) {
    float rs[4] = {0.f, 0.f, 0.f, 0.f};
    #pragma unroll
    for (int n = 0; n < 4; ++n)
      #pragma unroll
      for (int i = 0; i < 4; ++i) {
        float v = acc[m][n][i] + bias;
        float ax = fabsf(v);
        rs[i] += ax + __logf(1.0f + __expf(-2.0f * ax));
      }
    #pragma unroll
    for (int i = 0; i < 4; ++i) {
      float s = rs[i] - 4.0f * LN2F;
      s += __shfl_xor(s, 1);
      s += __shfl_xor(s, 2);
      s += __shfl_xor(s, 4);
      s += __shfl_xor(s, 8);
      if (lr == 0)
        atomicAdd(out + by * 256 + wm * 128 + m * 16 + lk * 4 + i, s);
    }
  }
}

// fallback if workspace is too small: correct but slow
__global__ void k_naive(const float* __restrict__ x, const float* __restrict__ W,
                        const float* __restrict__ bs, const float* __restrict__ vb,
                        float* __restrict__ out) {
  int b = blockIdx.x;
  __shared__ float xs[1024];
  __shared__ float red[256];
  int t = threadIdx.x;
  float xsum = 0.f;
  for (int i = t; i < 1024; i += 256) { float v = x[(size_t)b * 1024 + i]; xs[i] = v; xsum += v; }
  __syncthreads();
  float tot = vb[0] * xsum;
  for (int h = t; h < 16384; h += 256) {
    int j = h >> 10, kh = h & 1023;
    float a = bs[j];
    for (int i = 0; i < 1024; ++i) a += xs[i] * W[((i + kh) & 1023) * 16 + j];
    float ax = fabsf(a);
    tot += ax + __logf(1.f + __expf(-2.f * ax)) - LN2F;
  }
  red[t] = tot;
  __syncthreads();
  for (int s2 = 128; s2; s2 >>= 1) { if (t < s2) red[t] += red[t + s2]; __syncthreads(); }
  if (t == 0) out[b] = red[0];
}

extern "C" void kernel_launch(void* const* d_in, const int* in_sizes, int n_in,
                              void* d_out, int out_size, void* d_ws, size_t ws_size,
                              hipStream_t stream) {
  const float* x  = (const float*)d_in[0];
  const float* W  = (const float*)d_in[1];
  const float* bs = (const float*)d_in[2];
  const float* vb = (const float*)d_in[3];
  float* out = (float*)d_out;

  hipMemsetAsync(d_out, 0, (size_t)out_size * sizeof(float), stream);

  size_t need = ((size_t)8 << 20) + ((size_t)32 << 20);
  if (ws_size < need) {
    k_naive<<<4096, 256, 0, stream>>>(x, W, bs, vb, out);
    return;
  }

  __bf16* Xb = (__bf16*)d_ws;
  __bf16* Kb = (__bf16*)((char*)d_ws + ((size_t)8 << 20));

  k_cvt_x<<<2048, 256, 0, stream>>>(x, vb, Xb, out);
  k_expand2<<<512, 256, 0, stream>>>(W, Kb);

  k_gemm_lc6<<<1024, 512, 0, stream>>>(Xb, Kb, bs, out);
}